// Round 8
// baseline (156.041 us; speedup 1.0000x reference)
//
#include <hip/hip_runtime.h>
#include <stdint.h>

// RelativeAttention (Transformer-XL style), MI355X bf16-MFMA pipeline.
// SEQ=1024 RLEN=2048 BATCH=4 NH=16 DH=64 DM=1024.
// rel_shift derivation: shifted_bd[i,j] = BD[i, 1024 + j - i].

typedef __attribute__((ext_vector_type(8))) short v8s;   // 8 x bf16
typedef __attribute__((ext_vector_type(4))) float v4f;   // MFMA acc

__device__ __forceinline__ uint16_t f2b(float x) {       // f32 -> bf16 RNE
    uint32_t u = __builtin_bit_cast(uint32_t, x);
    u += 0x7fffu + ((u >> 16) & 1u);
    return (uint16_t)(u >> 16);
}

__device__ __forceinline__ void gld16(const void* g, void* lds) {
    __builtin_amdgcn_global_load_lds(
        (const __attribute__((address_space(1))) uint32_t*)g,
        (__attribute__((address_space(3))) uint32_t*)lds, 16, 0, 0);
}

// ---------------- prep: f32->bf16 casts (h, r, o_w) + weight transposes -----
__global__ __launch_bounds__(256) void prep_kernel(
    const float* __restrict__ h, const float* __restrict__ r,
    const float* __restrict__ o_w, const float* __restrict__ q_w,
    const float* __restrict__ k_w, const float* __restrict__ v_w,
    const float* __restrict__ r_w,
    uint64_t* __restrict__ hB, uint64_t* __restrict__ rB,
    uint64_t* __restrict__ owB, uint16_t* __restrict__ Wcat,
    uint16_t* __restrict__ rwT)
{
    __shared__ float t[64][65];
    const int bid = blockIdx.x, tid = threadIdx.x;
    if (bid < 1024) {
        const int tx = bid & 15, ty = (bid >> 4) & 15, z = bid >> 8;
        const int n0 = tx * 64, h0 = ty * 64;
        const float* src = (z == 0) ? q_w : (z == 1) ? k_w : (z == 2) ? v_w : r_w;
        uint16_t* dst = (z == 3) ? rwT : Wcat + (size_t)z * 1048576;
#pragma unroll
        for (int q = 0; q < 16; ++q) {
            int idx = q * 256 + tid, rr = idx >> 6, cc = idx & 63;
            t[rr][cc] = src[(size_t)(h0 + rr) * 1024 + n0 + cc];
        }
        __syncthreads();
#pragma unroll
        for (int q = 0; q < 16; ++q) {
            int idx = q * 256 + tid, rr = idx >> 6, cc = idx & 63;
            dst[(size_t)(n0 + rr) * 1024 + h0 + cc] = f2b(t[cc][rr]);
        }
    } else {
        const float4* h4 = (const float4*)h;
        const float4* r4 = (const float4*)r;
        const float4* w4 = (const float4*)o_w;
        const int total = 1048576 + 2097152 + 262144; // float4 chunks
        for (int i = (bid - 1024) * 256 + tid; i < total; i += 2048 * 256) {
            float4 v; uint64_t* dst; int idx;
            if (i < 1048576)      { idx = i;           v = h4[idx]; dst = hB; }
            else if (i < 3145728) { idx = i - 1048576; v = r4[idx]; dst = rB; }
            else                  { idx = i - 3145728; v = w4[idx]; dst = owB; }
            uint64_t p = (uint64_t)f2b(v.x) | ((uint64_t)f2b(v.y) << 16)
                       | ((uint64_t)f2b(v.z) << 32) | ((uint64_t)f2b(v.w) << 48);
            dst[idx] = p;
        }
    }
}

// ---------------- bf16 GEMM body, C = A[M,K] * B[N,K]^T, BMx128, BK=64 ------
// m97 structure: SINGLE-buffered LDS (32KB -> 5 blocks/CU; cross-block TLP
// covers the barrier drain — dbuf at 64KB/2 blocks/CU regressed, cf. m132).
template<int MODE, int MI>
__device__ __forceinline__ void gemm_body(
    const uint16_t* __restrict__ A, const uint16_t* __restrict__ B, int K,
    int bx, int by, uint16_t* As, uint16_t* Bs,
    uint16_t* __restrict__ o0, uint16_t* __restrict__ o1,
    uint16_t* __restrict__ o2, uint16_t* __restrict__ o3,
    const float* __restrict__ bias0, const float* __restrict__ bias1,
    float* __restrict__ fo, const float* __restrict__ fres)
{
    const int tid = threadIdx.x;
    const int w = tid >> 6, lane = tid & 63;
    const int g = lane >> 4, c15 = lane & 15;
    const int m0 = by * (MI * 32), n0 = bx * 128;
    const int wr = w >> 1, wc = w & 1;

    int rowA[MI], colA[MI];
#pragma unroll
    for (int q = 0; q < MI; ++q) {
        int D = (w * MI + q) * 1024 + lane * 16;
        int row = D >> 7;
        rowA[q] = row;
        colA[q] = (D & 127) ^ ((row & 7) << 4);
    }
    int rowB[4], colB[4];
#pragma unroll
    for (int q = 0; q < 4; ++q) {
        int D = (w * 4 + q) * 1024 + lane * 16;
        int row = D >> 7;
        rowB[q] = row;
        colB[q] = (D & 127) ^ ((row & 7) << 4);
    }

    v4f acc[MI][4];
#pragma unroll
    for (int i = 0; i < MI; ++i)
#pragma unroll
        for (int j = 0; j < 4; ++j) acc[i][j] = v4f{0.f, 0.f, 0.f, 0.f};

    const char* Abase = (const char*)(A + (size_t)m0 * K);
    const char* Bbase = (const char*)(B + (size_t)n0 * K);
    const size_t ld = (size_t)K * 2;

    for (int kb = 0; kb < K; kb += 64) {
        if (kb) __syncthreads();
#pragma unroll
        for (int q = 0; q < MI; ++q)
            gld16(Abase + (size_t)rowA[q] * ld + (size_t)kb * 2 + colA[q],
                  (char*)As + (w * MI + q) * 1024);
#pragma unroll
        for (int q = 0; q < 4; ++q)
            gld16(Bbase + (size_t)rowB[q] * ld + (size_t)kb * 2 + colB[q],
                  (char*)Bs + (w * 4 + q) * 1024);
        asm volatile("s_waitcnt vmcnt(0)" ::: "memory");
        __syncthreads();

        v8s af[MI][2], bf[4][2];
#pragma unroll
        for (int mi = 0; mi < MI; ++mi) {
            int row = wr * (MI * 16) + mi * 16 + c15;
#pragma unroll
            for (int ks = 0; ks < 2; ++ks) {
                int cl = ks * 64 + g * 16;
                af[mi][ks] = *(const v8s*)((const char*)As + row * 128 + (cl ^ ((row & 7) << 4)));
            }
        }
#pragma unroll
        for (int ni = 0; ni < 4; ++ni) {
            int row = wc * 64 + ni * 16 + c15;
#pragma unroll
            for (int ks = 0; ks < 2; ++ks) {
                int cl = ks * 64 + g * 16;
                bf[ni][ks] = *(const v8s*)((const char*)Bs + row * 128 + (cl ^ ((row & 7) << 4)));
            }
        }
#pragma unroll
        for (int mi = 0; mi < MI; ++mi)
#pragma unroll
            for (int ni = 0; ni < 4; ++ni)
#pragma unroll
                for (int ks = 0; ks < 2; ++ks)
                    acc[mi][ni] = __builtin_amdgcn_mfma_f32_16x16x32_bf16(
                        af[mi][ks], bf[ni][ks], acc[mi][ni], 0, 0, 0);
    }

#pragma unroll
    for (int mi = 0; mi < MI; ++mi)
#pragma unroll
        for (int ni = 0; ni < 4; ++ni)
#pragma unroll
            for (int t = 0; t < 4; ++t) {
                int row = m0 + wr * (MI * 16) + mi * 16 + g * 4 + t; // C row
                int col = n0 + wc * 64 + ni * 16 + c15;              // C col
                float v = acc[mi][ni][t];
                if (MODE == 0) {
                    int seg = col >> 10, nd = col & 1023;
                    int i = row >> 2, b = row & 3, n = nd >> 6, d = nd & 63;
                    int bn = b * 16 + n;
                    if (seg == 0) {
                        o0[(bn << 16) + (i << 6) + d] = f2b(v + bias0[nd]);
                        o1[(bn << 16) + (i << 6) + d] = f2b(v + bias1[nd]);
                    } else if (seg == 1) {
                        o2[(bn << 16) + (i << 6) + d] = f2b(v);
                    } else {
                        // V transposed + j-permuted within each 64-block:
                        // j = f*16+c stored at position c*4+f (must match P store)
                        int il = i & 63;
                        int iperm = (i & ~63) | ((il & 15) * 4 + (il >> 4));
                        o3[(bn << 16) + (d << 10) + iperm] = f2b(v);
                    }
                } else if (MODE == 1) {
                    int j = row >> 2, b = row & 3, n = col >> 6, d = col & 63;
                    int bn = b * 16 + n;
                    o0[(bn << 17) + (j << 6) + d] = f2b(v);
                } else {
                    size_t idx = (size_t)row * 1024 + col;
                    fo[idx] = v + fres[idx];   // residual add in f32
                }
            }
}

// merged projection GEMMs, 2D-XCD-swizzled (bid%8 = XCD)
__global__ __launch_bounds__(256) void gemm_qkvr(
    const uint16_t* __restrict__ hB, const uint16_t* __restrict__ Wcat,
    const uint16_t* __restrict__ rB, const uint16_t* __restrict__ rwT,
    uint16_t* __restrict__ Qw, uint16_t* __restrict__ Qr,
    uint16_t* __restrict__ Kt, uint16_t* __restrict__ Vt,
    uint16_t* __restrict__ Kr,
    const float* __restrict__ b0, const float* __restrict__ b1)
{
    __shared__ __align__(16) uint16_t As[128 * 64];
    __shared__ __align__(16) uint16_t Bs[128 * 64];
    const int bid = blockIdx.x;
    if (bid < 768) {
        const int x = bid & 7, l = bid >> 3;          // l in [0,96)
        const int by = (x >> 1) * 8 + l / 12;
        const int bx = (x & 1) * 12 + l % 12;
        gemm_body<0, 4>(hB, Wcat, 1024, bx, by, As, Bs,
                        Qw, Qr, Kt, Vt, b0, b1, nullptr, nullptr);
    } else {
        const int b2 = bid - 768;
        const int x = b2 & 7, l = b2 >> 3;            // l in [0,64)
        const int by = x * 8 + l / 8;
        const int bx = l % 8;
        gemm_body<1, 4>(rB, rwT, 1024, bx, by, As, Bs,
                        Kr, nullptr, nullptr, nullptr, nullptr, nullptr,
                        nullptr, nullptr);
    }
}

// out proj: BM=64 tiles -> 512 blocks, XCD x owns m-rows [8x,+8)
__global__ __launch_bounds__(256) void gemm_out(
    const uint16_t* __restrict__ AV, const uint16_t* __restrict__ owB,
    float* __restrict__ AO, const float* __restrict__ hres)
{
    __shared__ __align__(16) uint16_t As[64 * 64];
    __shared__ __align__(16) uint16_t Bs[128 * 64];
    const int x = blockIdx.x & 7, l = blockIdx.x >> 3;  // l in [0,64)
    const int by = x * 8 + l / 8;
    const int bx = l % 8;
    gemm_body<2, 2>(AV, owB, 1024, bx, by, As, Bs,
                    nullptr, nullptr, nullptr, nullptr, nullptr, nullptr,
                    AO, hres);
}

// ---------------- fused rel-shift flash attention ---------------------------
// Grid 512 blocks x 256 threads (4 waves); XCD-swizzled; 2 blocks/CU
// (80KB LDS), 8 waves/CU. Each wave owns a 32-row strip (2 mi sub-strips of
// 16) — amortizes per-wave K/V/Kr LDS fragment reads across 2x the rows
// (DS-pipe is the bottleneck). Per j-tile: double-buffered K/V staging +
// 256-row Kr ring via global_load_lds with pre-swizzled source; one 96-row
// Kr window serves both sub-strips (pf 0..5; mi0 uses pf1..5, mi1 pf0..4);
// rel-shift via 40 lane shuffles; FIXED-max softmax (M=8, exact by shift
// invariance); P stored j-permuted per mi-half via v_cvt_pk_bf16_f32; V
// permuted identically in gemm<0>.
__global__ __launch_bounds__(256, 2) void attn_kernel(
    const uint16_t* __restrict__ Qw, const uint16_t* __restrict__ Qr,
    const uint16_t* __restrict__ Kt, const uint16_t* __restrict__ Vt,
    const uint16_t* __restrict__ Kr, uint16_t* __restrict__ AV)
{
    __shared__ __align__(16) uint16_t Ks[2][4096];   // 8KB ea: 64 j x 64 d
    __shared__ __align__(16) uint16_t Vs[2][4096];   // 8KB ea: 64 d x 64 j'
    __shared__ __align__(16) uint16_t Krs[16384];    // 32KB ring: 256 rows
    __shared__ __align__(16) uint16_t Ptl[4][2048];  // 16KB: per-wave 2x16x64

    const int tid = threadIdx.x, w = tid >> 6, lane = tid & 63;
    const int g = lane >> 4, c15 = lane & 15;
    const int bid = blockIdx.x;
    const int xcd = bid & 7, slot = bid >> 3;
    const int it = slot & 7, bn = ((slot >> 3) << 3) | xcd;
    const int b = bn >> 4, n = bn & 15;
    const int i0 = it * 128, i0w = i0 + w * 32;
    const int B0 = 897 - i0;                 // lowest Kr row of jt=0 window

    const uint16_t* qwp = Qw + ((size_t)bn << 16);
    const uint16_t* qrp = Qr + ((size_t)bn << 16);
    const char* ktp = (const char*)(Kt + ((size_t)bn << 16));
    const char* vtp = (const char*)(Vt + ((size_t)bn << 16));
    const char* krp = (const char*)(Kr + ((size_t)bn << 17));

    const int rsub = lane >> 3;              // staging: row-within-8-chunk
    const int csrc = ((lane & 7) ^ rsub) << 4;  // pre-swizzled source col
    const int dsto = lane * 16;              // linear LDS dest
    const int swz = (c15 & 7) << 4;          // read-side XOR term

    // rel-shift shuffle constants: e = 15 + c15 - (g*4+t)  (mi-invariant)
    int sl[4], esel[4];
#pragma unroll
    for (int t = 0; t < 4; ++t) {
        int e = 15 + c15 - (g * 4 + t);
        sl[t] = g * 16 + (e & 15);
        esel[t] = e >> 4;
    }

    v8s qwf[2][2], qrf[2][2];
#pragma unroll
    for (int mi = 0; mi < 2; ++mi)
#pragma unroll
        for (int ks = 0; ks < 2; ++ks) {
            qwf[mi][ks] = *(const v8s*)(qwp + ((i0w + mi * 16 + c15) << 6) + ks * 32 + g * 8);
            qrf[mi][ks] = *(const v8s*)(qrp + ((i0w + mi * 16 + c15) << 6) + ks * 32 + g * 8);
        }

    v4f acc_o[2][4];
    float psac[2][4];
#pragma unroll
    for (int mi = 0; mi < 2; ++mi)
#pragma unroll
        for (int df = 0; df < 4; ++df) {
            acc_o[mi][df] = v4f{0.f, 0.f, 0.f, 0.f};
            psac[mi][df] = 0.f;
        }

    uint16_t* Ptw = Ptl[w];
    const float SCL = 0.18033688f;   // 0.125 * log2(e)
    const float MB8 = 11.54156032f;  // 8 * log2(e)

    // ---- prologue staging: K/V tile 0 (chunks w, w+4) + Kr rows B0..B0+191
#pragma unroll
    for (int qq = 0; qq < 2; ++qq) {
        const int chunk = qq * 4 + w;
        gld16(ktp + (size_t)(chunk * 8 + rsub) * 128 + csrc,
              (char*)Ks[0] + chunk * 1024 + dsto);
        gld16(vtp + (size_t)(chunk * 8 + rsub) * 2048 + csrc,
              (char*)Vs[0] + chunk * 1024 + dsto);
    }
#pragma unroll
    for (int qq = 0; qq < 6; ++qq) {
        const int chunk = qq * 4 + w;
        const int rg = B0 + chunk * 8 + rsub;   // in [1, 1088]
        gld16(krp + (size_t)rg * 128 + csrc, (char*)Krs + chunk * 1024 + dsto);
    }
    asm volatile("s_waitcnt vmcnt(0)" ::: "memory");
    __syncthreads();

    for (int jt = 0; jt < 16; ++jt) {
        const int cur = jt & 1;
        if (jt < 15) {
            const int j1 = (jt + 1) * 64;
            const int sbase = (192 + 64 * jt) & 255;   // ring write slots
#pragma unroll
            for (int qq = 0; qq < 2; ++qq) {
                const int chunk = qq * 4 + w;
                gld16(ktp + (size_t)(j1 + chunk * 8 + rsub) * 128 + csrc,
                      (char*)Ks[cur ^ 1] + chunk * 1024 + dsto);
                gld16(vtp + (size_t)(chunk * 8 + rsub) * 2048 + j1 * 2 + csrc,
                      (char*)Vs[cur ^ 1] + chunk * 1024 + dsto);
                int rg = B0 + 192 + 64 * jt + chunk * 8 + rsub;
                rg = rg > 2047 ? 2047 : rg;  // clamp: only u=95 (never gathered)
                gld16(krp + (size_t)rg * 128 + csrc,
                      (char*)Krs + (sbase + chunk * 8) * 128 + dsto);
            }
        }

        // --- AC = Qw x K^T (2 mi x 64 cols), K-frags shared across mi ---
        v4f ac[2][4];
#pragma unroll
        for (int mi = 0; mi < 2; ++mi)
#pragma unroll
            for (int jf = 0; jf < 4; ++jf) ac[mi][jf] = v4f{0.f, 0.f, 0.f, 0.f};

        __builtin_amdgcn_s_setprio(1);
#pragma unroll
        for (int jf = 0; jf < 4; ++jf) {
            const char* krow = (const char*)Ks[cur] + (jf * 16 + c15) * 128;
#pragma unroll
            for (int ks = 0; ks < 2; ++ks) {
                v8s kf = *(const v8s*)(krow + ((ks * 64 + g * 16) ^ swz));
                ac[0][jf] = __builtin_amdgcn_mfma_f32_16x16x32_bf16(qwf[0][ks], kf, ac[0][jf], 0, 0, 0);
                ac[1][jf] = __builtin_amdgcn_mfma_f32_16x16x32_bf16(qwf[1][ks], kf, ac[1][jf], 0, 0, 0);
            }
        }
        // --- BD: one 96-row Kr window serves both mi (pf 0..5 shared) ---
        // pp0[k] = P(mi0, pf=k+1), pp1[k] = P(mi1, pf=k)
        v4f pp0[5], pp1[5];
#pragma unroll
        for (int pf = 0; pf < 5; ++pf) {
            pp0[pf] = v4f{0.f, 0.f, 0.f, 0.f};
            pp1[pf] = v4f{0.f, 0.f, 0.f, 0.f};
        }
        const int krbase = 64 * jt + 96 - 32 * w + c15;  // ring slot (+c15)
#pragma unroll
        for (int pf = 0; pf < 6; ++pf) {
            const int sltr = (krbase + 16 * pf) & 255;
            const char* krow = (const char*)Krs + sltr * 128;
#pragma unroll
            for (int ks = 0; ks < 2; ++ks) {
                v8s krf = *(const v8s*)(krow + ((ks * 64 + g * 16) ^ swz));
                if (pf >= 1)
                    pp0[pf - 1] = __builtin_amdgcn_mfma_f32_16x16x32_bf16(qrf[0][ks], krf, pp0[pf - 1], 0, 0, 0);
                if (pf <= 4)
                    pp1[pf] = __builtin_amdgcn_mfma_f32_16x16x32_bf16(qrf[1][ks], krf, pp1[pf], 0, 0, 0);
            }
        }
        __builtin_amdgcn_s_setprio(0);

        // --- rel-shift gather (per mi; sl is mi-invariant) ---
        float spp0[5][4], spp1[5][4];
#pragma unroll
        for (int pf = 0; pf < 5; ++pf)
#pragma unroll
            for (int t = 0; t < 4; ++t) {
                spp0[pf][t] = __shfl(pp0[pf][t], sl[t]);
                spp1[pf][t] = __shfl(pp1[pf][t], sl[t]);
            }

        // --- fixed-max softmax + packed P store, per mi-half ---
#pragma unroll
        for (int mi = 0; mi < 2; ++mi) {
#pragma unroll
            for (int t = 0; t < 4; ++t) {
                float p[4];
#pragma unroll
                for (int jf = 0; jf < 4; ++jf) {
                    float bd = mi ? (esel[t] ? spp1[jf + 1][t] : spp1[jf][t])
                                  : (esel[t] ? spp0[jf + 1][t] : spp0[jf][t]);
                    p[jf] = exp2f((ac[mi][jf][t] + bd) * SCL - MB8);
                    psac[mi][t] += p[jf];
                }
                uint32_t w0, w1;
                asm("v_cvt_pk_bf16_f32 %0, %1, %2" : "=v"(w0) : "v"(p[0]), "v"(p[1]));
                asm("v_cvt_pk_bf16_f32 %0, %1, %2" : "=v"(w1) : "v"(p[2]), "v"(p[3]));
                const int rw = g * 4 + t;
                *(uint2*)((char*)Ptw + mi * 2048 + rw * 128 + ((c15 * 8) ^ ((rw & 7) << 4))) =
                    uint2{w0, w1};
            }
        }
        asm volatile("s_waitcnt lgkmcnt(0)" ::: "memory");

        // --- PV: A-frags from Ptw halves, V-frags shared across mi ---
        v8s pa[2][2];
#pragma unroll
        for (int mi = 0; mi < 2; ++mi)
#pragma unroll
            for (int ks = 0; ks < 2; ++ks)
                pa[mi][ks] = *(const v8s*)((const char*)Ptw + mi * 2048 + c15 * 128 + ((ks * 64 + g * 16) ^ swz));
        __builtin_amdgcn_s_setprio(1);
#pragma unroll
        for (int df = 0; df < 4; ++df) {
            const char* vrow = (const char*)Vs[cur] + (df * 16 + c15) * 128;
#pragma unroll
            for (int ks = 0; ks < 2; ++ks) {
                v8s vf = *(const v8s*)(vrow + ((ks * 64 + g * 16) ^ swz));
                acc_o[0][df] = __builtin_amdgcn_mfma_f32_16x16x32_bf16(pa[0][ks], vf, acc_o[0][df], 0, 0, 0);
                acc_o[1][df] = __builtin_amdgcn_mfma_f32_16x16x32_bf16(pa[1][ks], vf, acc_o[1][df], 0, 0, 0);
            }
        }
        __builtin_amdgcn_s_setprio(0);

        asm volatile("s_waitcnt vmcnt(0)" ::: "memory");
        __syncthreads();
    }

    // ---- epilogue: row-sum reduce (across c15 lanes), divide, store ----
#pragma unroll
    for (int mi = 0; mi < 2; ++mi) {
        float rinv[4];
#pragma unroll
        for (int t = 0; t < 4; ++t) {
            float l = psac[mi][t];
#pragma unroll
            for (int m = 1; m < 16; m <<= 1) l += __shfl_xor(l, m);
            rinv[t] = 1.0f / l;
        }
#pragma unroll
        for (int df = 0; df < 4; ++df)
#pragma unroll
            for (int t = 0; t < 4; ++t) {
                int i = i0w + mi * 16 + g * 4 + t;
                int d = df * 16 + c15;
                AV[((size_t)(i * 4 + b) << 10) + n * 64 + d] =
                    f2b(acc_o[mi][df][t] * rinv[t]);
            }
    }
}

// ---------------- LayerNorm over last dim (1024), one row per wave ----------
__global__ __launch_bounds__(256) void ln_kernel(
    const float* __restrict__ AO, const float* __restrict__ gamma,
    const float* __restrict__ beta, float* __restrict__ out)
{
    const int w = threadIdx.x >> 6, lane = threadIdx.x & 63;
    const int row = blockIdx.x * 4 + w;
    const float4* src = (const float4*)(AO + (size_t)row * 1024);
    float4 v[4];
    float s = 0.f, sq = 0.f;
#pragma unroll
    for (int q = 0; q < 4; ++q) {
        v[q] = src[lane + q * 64];
        s += v[q].x + v[q].y + v[q].z + v[q].w;
        sq += v[q].x * v[q].x + v[q].y * v[q].y + v[q].z * v[q].z + v[q].w * v[q].w;
    }
#pragma unroll
    for (int m = 1; m < 64; m <<= 1) { s += __shfl_xor(s, m); sq += __shfl_xor(sq, m); }
    float mean = s * (1.f / 1024.f);
    float var = sq * (1.f / 1024.f) - mean * mean;
    float rstd = rsqrtf(var + 1e-5f);
    const float4* g4 = (const float4*)gamma;
    const float4* b4 = (const float4*)beta;
    float4* o4 = (float4*)(out + (size_t)row * 1024);
#pragma unroll
    for (int q = 0; q < 4; ++q) {
        float4 gg = g4[lane + q * 64], bb = b4[lane + q * 64], vv = v[q], r;
        r.x = (vv.x - mean) * rstd * gg.x + bb.x;
        r.y = (vv.y - mean) * rstd * gg.y + bb.y;
        r.z = (vv.z - mean) * rstd * gg.z + bb.z;
        r.w = (vv.w - mean) * rstd * gg.w + bb.w;
        o4[lane + q * 64] = r;
    }
}

extern "C" void kernel_launch(void* const* d_in, const int* in_sizes, int n_in,
                              void* d_out, int out_size, void* d_ws, size_t ws_size,
                              hipStream_t stream)
{
    const float* h        = (const float*)d_in[0];
    const float* r        = (const float*)d_in[1];
    const float* q_w      = (const float*)d_in[2];
    const float* k_w      = (const float*)d_in[3];
    const float* v_w      = (const float*)d_in[4];
    const float* o_w      = (const float*)d_in[5];
    const float* r_w      = (const float*)d_in[6];
    const float* r_r_bias = (const float*)d_in[7];
    const float* r_w_bias = (const float*)d_in[8];
    const float* ln_gamma = (const float*)d_in[9];
    const float* ln_beta  = (const float*)d_in[10];
    float* out = (float*)d_out;

    char* ws = (char*)d_ws;
    const size_t MB = 1u << 20;
    uint16_t* hB   = (uint16_t*)(ws + 0);        // 8MB  [m][k] bf16 (m = i*4+b)
    uint16_t* rB   = (uint16_t*)(ws + 8 * MB);   // 16MB [m][k] bf16 (m = j*4+b)
    uint16_t* Wcat = (uint16_t*)(ws + 24 * MB);  // 6MB  [nd' 0..3071][h] (qT,kT,vT)
    uint16_t* rwT  = (uint16_t*)(ws + 30 * MB);  // 2MB  [nd][h]
    uint16_t* owB  = (uint16_t*)(ws + 32 * MB);  // 2MB  [hh][nd]
    uint16_t* Qw   = (uint16_t*)(ws + 34 * MB);  // 8MB  [bn][i][d] (+r_w_bias)
    uint16_t* Qr   = (uint16_t*)(ws + 42 * MB);  // 8MB  [bn][i][d] (+r_r_bias)
    uint16_t* Kt   = (uint16_t*)(ws + 50 * MB);  // 8MB  [bn][i][d]
    uint16_t* Vt   = (uint16_t*)(ws + 58 * MB);  // 8MB  [bn][d][i'] (transp+perm)
    uint16_t* Kr   = (uint16_t*)(ws + 66 * MB);  // 16MB [bn][j][d]   (ends 82MB)
    uint16_t* AV   = hB;          // alias: hB dead after gemm_qkvr
    float*    AO   = (float*)rB;  // alias: rB dead after gemm_qkvr

    prep_kernel<<<3072, 256, 0, stream>>>(h, r, o_w, q_w, k_w, v_w, r_w,
                                          (uint64_t*)hB, (uint64_t*)rB,
                                          (uint64_t*)owB, Wcat, rwT);
    gemm_qkvr<<<1280, 256, 0, stream>>>(hB, Wcat, rB, rwT,
                                        Qw, Qr, Kt, Vt, Kr, r_w_bias, r_r_bias);
    attn_kernel<<<512, 256, 0, stream>>>(Qw, Qr, Kt, Vt, Kr, AV);
    gemm_out<<<512, 256, 0, stream>>>(AV, owB, AO, h);
    ln_kernel<<<1024, 256, 0, stream>>>(AO, ln_gamma, ln_beta, out);
}

// Round 9
// 154.041 us; speedup vs baseline: 1.0130x; 1.0130x over previous
//
#include <hip/hip_runtime.h>
#include <stdint.h>

// RelativeAttention (Transformer-XL style), MI355X bf16-MFMA pipeline.
// SEQ=1024 RLEN=2048 BATCH=4 NH=16 DH=64 DM=1024.
// rel_shift derivation: shifted_bd[i,j] = BD[i, 1024 + j - i].

typedef __attribute__((ext_vector_type(8))) short v8s;    // 8 x bf16
typedef __attribute__((ext_vector_type(4))) float v4f;    // MFMA acc
typedef __attribute__((ext_vector_type(4))) uint32_t v4u; // 16B LDS store

__device__ __forceinline__ uint16_t f2b(float x) {       // f32 -> bf16 RNE
    uint32_t u = __builtin_bit_cast(uint32_t, x);
    u += 0x7fffu + ((u >> 16) & 1u);
    return (uint16_t)(u >> 16);
}

__device__ __forceinline__ uint32_t cvtpk(float lo, float hi) {
    uint32_t r;
    asm("v_cvt_pk_bf16_f32 %0, %1, %2" : "=v"(r) : "v"(lo), "v"(hi));
    return r;
}

__device__ __forceinline__ void gld16(const void* g, void* lds) {
    __builtin_amdgcn_global_load_lds(
        (const __attribute__((address_space(1))) uint32_t*)g,
        (__attribute__((address_space(3))) uint32_t*)lds, 16, 0, 0);
}

// ---------------- prep: weight transposes + o_w cast ------------------------
// blocks [0,1024): transpose q_w/k_w/v_w/r_w [h][nd] -> [nd][h] bf16
// blocks [1024,1536): straight cast o_w -> owB
__global__ __launch_bounds__(256) void prep_kernel(
    const float* __restrict__ o_w, const float* __restrict__ q_w,
    const float* __restrict__ k_w, const float* __restrict__ v_w,
    const float* __restrict__ r_w,
    uint64_t* __restrict__ owB, uint16_t* __restrict__ Wcat,
    uint16_t* __restrict__ rwT)
{
    __shared__ float t[64][65];
    const int bid = blockIdx.x, tid = threadIdx.x;
    if (bid < 1024) {
        const int tx = bid & 15, ty = (bid >> 4) & 15, z = bid >> 8;
        const int n0 = tx * 64, h0 = ty * 64;
        const float* src = (z == 0) ? q_w : (z == 1) ? k_w : (z == 2) ? v_w : r_w;
        uint16_t* dst = (z == 3) ? rwT : Wcat + (size_t)z * 1048576;
#pragma unroll
        for (int q = 0; q < 16; ++q) {
            int idx = q * 256 + tid, rr = idx >> 6, cc = idx & 63;
            t[rr][cc] = src[(size_t)(h0 + rr) * 1024 + n0 + cc];
        }
        __syncthreads();
#pragma unroll
        for (int q = 0; q < 16; ++q) {
            int idx = q * 256 + tid, rr = idx >> 6, cc = idx & 63;
            dst[(size_t)(n0 + rr) * 1024 + h0 + cc] = f2b(t[cc][rr]);
        }
    } else {
        const float4* w4 = (const float4*)o_w;
        const int total = 262144; // float4 chunks of o_w
        for (int i = (bid - 1024) * 256 + tid; i < total; i += 512 * 256) {
            float4 v = w4[i];
            owB[i] = (uint64_t)f2b(v.x) | ((uint64_t)f2b(v.y) << 16)
                   | ((uint64_t)f2b(v.z) << 32) | ((uint64_t)f2b(v.w) << 48);
        }
    }
}

// ---------------- bf16 GEMM body, C = A[M,K] * B[N,K]^T, BMx128, BK=64 ------
// m97 structure: SINGLE-buffered LDS (32KB -> high blocks/CU; cross-block TLP
// covers the barrier drain — dbuf regressed, cf. m132).
// AF32: A is f32 in global; staged via reg (f32x8 -> cvt_pk -> ds_write_b128)
// into the SAME swizzled LDS image — fuses the bf16 cast into the GEMM.
template<int MODE, int MI, bool AF32>
__device__ __forceinline__ void gemm_body(
    const void* __restrict__ A, const uint16_t* __restrict__ B, int K,
    int bx, int by, uint16_t* As, uint16_t* Bs,
    uint16_t* __restrict__ o0, uint16_t* __restrict__ o1,
    uint16_t* __restrict__ o2, uint16_t* __restrict__ o3,
    const float* __restrict__ bias0, const float* __restrict__ bias1,
    float* __restrict__ fo, const float* __restrict__ fres)
{
    const int tid = threadIdx.x;
    const int w = tid >> 6, lane = tid & 63;
    const int g = lane >> 4, c15 = lane & 15;
    const int m0 = by * (MI * 32), n0 = bx * 128;
    const int wr = w >> 1, wc = w & 1;

    // staging maps: LDS phys byte D holds X[row][ (D&127) ^ ((row&7)<<4) ]
    int rowA[MI], colA[MI];
#pragma unroll
    for (int q = 0; q < MI; ++q) {
        int D = (w * MI + q) * 1024 + lane * 16;
        int row = D >> 7;
        rowA[q] = row;
        colA[q] = (D & 127) ^ ((row & 7) << 4);   // logical bf16 byte-col
    }
    int rowB[4], colB[4];
#pragma unroll
    for (int q = 0; q < 4; ++q) {
        int D = (w * 4 + q) * 1024 + lane * 16;
        int row = D >> 7;
        rowB[q] = row;
        colB[q] = (D & 127) ^ ((row & 7) << 4);
    }

    v4f acc[MI][4];
#pragma unroll
    for (int i = 0; i < MI; ++i)
#pragma unroll
        for (int j = 0; j < 4; ++j) acc[i][j] = v4f{0.f, 0.f, 0.f, 0.f};

    const char* Abase;
    size_t lda;
    if constexpr (AF32) {
        Abase = (const char*)((const float*)A + (size_t)m0 * K);
        lda = (size_t)K * 4;
    } else {
        Abase = (const char*)((const uint16_t*)A + (size_t)m0 * K);
        lda = (size_t)K * 2;
    }
    const char* Bbase = (const char*)(B + (size_t)n0 * K);
    const size_t ldb = (size_t)K * 2;

    for (int kb = 0; kb < K; kb += 64) {
        if (kb) __syncthreads();
#pragma unroll
        for (int q = 0; q < 4; ++q)
            gld16(Bbase + (size_t)rowB[q] * ldb + (size_t)kb * 2 + colB[q],
                  (char*)Bs + (w * 4 + q) * 1024);
        if constexpr (AF32) {
            float4 f[MI][2];
#pragma unroll
            for (int q = 0; q < MI; ++q) {
                const char* src = Abase + (size_t)rowA[q] * lda
                                + (size_t)kb * 4 + colA[q] * 2;
                f[q][0] = *(const float4*)src;
                f[q][1] = *(const float4*)(src + 16);
            }
#pragma unroll
            for (int q = 0; q < MI; ++q) {
                v4u pk;
                pk.x = cvtpk(f[q][0].x, f[q][0].y);
                pk.y = cvtpk(f[q][0].z, f[q][0].w);
                pk.z = cvtpk(f[q][1].x, f[q][1].y);
                pk.w = cvtpk(f[q][1].z, f[q][1].w);
                *(v4u*)((char*)As + (w * MI + q) * 1024 + lane * 16) = pk;
            }
        } else {
#pragma unroll
            for (int q = 0; q < MI; ++q)
                gld16(Abase + (size_t)rowA[q] * lda + (size_t)kb * 2 + colA[q],
                      (char*)As + (w * MI + q) * 1024);
        }
        asm volatile("s_waitcnt vmcnt(0)" ::: "memory");
        __syncthreads();

        v8s af[MI][2], bf[4][2];
#pragma unroll
        for (int mi = 0; mi < MI; ++mi) {
            int row = wr * (MI * 16) + mi * 16 + c15;
#pragma unroll
            for (int ks = 0; ks < 2; ++ks) {
                int cl = ks * 64 + g * 16;
                af[mi][ks] = *(const v8s*)((const char*)As + row * 128 + (cl ^ ((row & 7) << 4)));
            }
        }
#pragma unroll
        for (int ni = 0; ni < 4; ++ni) {
            int row = wc * 64 + ni * 16 + c15;
#pragma unroll
            for (int ks = 0; ks < 2; ++ks) {
                int cl = ks * 64 + g * 16;
                bf[ni][ks] = *(const v8s*)((const char*)Bs + row * 128 + (cl ^ ((row & 7) << 4)));
            }
        }
#pragma unroll
        for (int mi = 0; mi < MI; ++mi)
#pragma unroll
            for (int ni = 0; ni < 4; ++ni)
#pragma unroll
                for (int ks = 0; ks < 2; ++ks)
                    acc[mi][ni] = __builtin_amdgcn_mfma_f32_16x16x32_bf16(
                        af[mi][ks], bf[ni][ks], acc[mi][ni], 0, 0, 0);
    }

#pragma unroll
    for (int mi = 0; mi < MI; ++mi)
#pragma unroll
        for (int ni = 0; ni < 4; ++ni)
#pragma unroll
            for (int t = 0; t < 4; ++t) {
                int row = m0 + wr * (MI * 16) + mi * 16 + g * 4 + t; // C row
                int col = n0 + wc * 64 + ni * 16 + c15;              // C col
                float v = acc[mi][ni][t];
                if (MODE == 0) {
                    int seg = col >> 10, nd = col & 1023;
                    int i = row >> 2, b = row & 3, n = nd >> 6, d = nd & 63;
                    int bn = b * 16 + n;
                    if (seg == 0) {
                        o0[(bn << 16) + (i << 6) + d] = f2b(v + bias0[nd]);
                        o1[(bn << 16) + (i << 6) + d] = f2b(v + bias1[nd]);
                    } else if (seg == 1) {
                        o2[(bn << 16) + (i << 6) + d] = f2b(v);
                    } else {
                        // V transposed + j-permuted within each 64-block:
                        // j = f*16+c stored at position c*4+f (must match P store)
                        int il = i & 63;
                        int iperm = (i & ~63) | ((il & 15) * 4 + (il >> 4));
                        o3[(bn << 16) + (d << 10) + iperm] = f2b(v);
                    }
                } else if (MODE == 1) {
                    int j = row >> 2, b = row & 3, n = col >> 6, d = col & 63;
                    int bn = b * 16 + n;
                    o0[(bn << 17) + (j << 6) + d] = f2b(v);
                } else {
                    size_t idx = (size_t)row * 1024 + col;
                    fo[idx] = v + fres[idx];   // residual add in f32
                }
            }
}

// merged projection GEMMs, 2D-XCD-swizzled (bid%8 = XCD); A read directly
// from f32 h / r (cast fused into staging — no hB/rB round-trip).
__global__ __launch_bounds__(256) void gemm_qkvr(
    const float* __restrict__ h, const uint16_t* __restrict__ Wcat,
    const float* __restrict__ r, const uint16_t* __restrict__ rwT,
    uint16_t* __restrict__ Qw, uint16_t* __restrict__ Qr,
    uint16_t* __restrict__ Kt, uint16_t* __restrict__ Vt,
    uint16_t* __restrict__ Kr,
    const float* __restrict__ b0, const float* __restrict__ b1)
{
    __shared__ __align__(16) uint16_t As[128 * 64];
    __shared__ __align__(16) uint16_t Bs[128 * 64];
    const int bid = blockIdx.x;
    if (bid < 768) {
        const int x = bid & 7, l = bid >> 3;          // l in [0,96)
        const int by = (x >> 1) * 8 + l / 12;
        const int bx = (x & 1) * 12 + l % 12;
        gemm_body<0, 4, true>(h, Wcat, 1024, bx, by, As, Bs,
                              Qw, Qr, Kt, Vt, b0, b1, nullptr, nullptr);
    } else {
        const int b2 = bid - 768;
        const int x = b2 & 7, l = b2 >> 3;            // l in [0,64)
        const int by = x * 8 + l / 8;
        const int bx = l % 8;
        gemm_body<1, 4, true>(r, rwT, 1024, bx, by, As, Bs,
                              Kr, nullptr, nullptr, nullptr, nullptr, nullptr,
                              nullptr, nullptr);
    }
}

// out proj: BM=64 tiles -> 512 blocks, XCD x owns m-rows [8x,+8)
__global__ __launch_bounds__(256) void gemm_out(
    const uint16_t* __restrict__ AV, const uint16_t* __restrict__ owB,
    float* __restrict__ AO, const float* __restrict__ hres)
{
    __shared__ __align__(16) uint16_t As[64 * 64];
    __shared__ __align__(16) uint16_t Bs[128 * 64];
    const int x = blockIdx.x & 7, l = blockIdx.x >> 3;  // l in [0,64)
    const int by = x * 8 + l / 8;
    const int bx = l % 8;
    gemm_body<2, 2, false>(AV, owB, 1024, bx, by, As, Bs,
                           nullptr, nullptr, nullptr, nullptr, nullptr, nullptr,
                           AO, hres);
}

// ---------------- fused rel-shift flash attention ---------------------------
// Grid 512 blocks x 256 threads (4 waves); XCD-swizzled; 2 blocks/CU
// (80KB LDS), 8 waves/CU. Each wave owns a 32-row strip (2 mi sub-strips of
// 16) — amortizes per-wave K/V/Kr LDS fragment reads across 2x the rows.
// Per j-tile: double-buffered K/V staging + 256-row Kr ring via
// global_load_lds with pre-swizzled source; one 96-row Kr window serves both
// sub-strips (pf 0..5; mi0 uses pf1..5, mi1 pf0..4); rel-shift via 40 lane
// shuffles; FIXED-max softmax (M=8, exact by shift invariance); P stored
// j-permuted per mi-half via v_cvt_pk_bf16_f32; V permuted identically in
// gemm<0>.
__global__ __launch_bounds__(256, 2) void attn_kernel(
    const uint16_t* __restrict__ Qw, const uint16_t* __restrict__ Qr,
    const uint16_t* __restrict__ Kt, const uint16_t* __restrict__ Vt,
    const uint16_t* __restrict__ Kr, uint16_t* __restrict__ AV)
{
    __shared__ __align__(16) uint16_t Ks[2][4096];   // 8KB ea: 64 j x 64 d
    __shared__ __align__(16) uint16_t Vs[2][4096];   // 8KB ea: 64 d x 64 j'
    __shared__ __align__(16) uint16_t Krs[16384];    // 32KB ring: 256 rows
    __shared__ __align__(16) uint16_t Ptl[4][2048];  // 16KB: per-wave 2x16x64

    const int tid = threadIdx.x, w = tid >> 6, lane = tid & 63;
    const int g = lane >> 4, c15 = lane & 15;
    const int bid = blockIdx.x;
    const int xcd = bid & 7, slot = bid >> 3;
    const int it = slot & 7, bn = ((slot >> 3) << 3) | xcd;
    const int b = bn >> 4, n = bn & 15;
    const int i0 = it * 128, i0w = i0 + w * 32;
    const int B0 = 897 - i0;                 // lowest Kr row of jt=0 window

    const uint16_t* qwp = Qw + ((size_t)bn << 16);
    const uint16_t* qrp = Qr + ((size_t)bn << 16);
    const char* ktp = (const char*)(Kt + ((size_t)bn << 16));
    const char* vtp = (const char*)(Vt + ((size_t)bn << 16));
    const char* krp = (const char*)(Kr + ((size_t)bn << 17));

    const int rsub = lane >> 3;              // staging: row-within-8-chunk
    const int csrc = ((lane & 7) ^ rsub) << 4;  // pre-swizzled source col
    const int dsto = lane * 16;              // linear LDS dest
    const int swz = (c15 & 7) << 4;          // read-side XOR term

    // rel-shift shuffle constants: e = 15 + c15 - (g*4+t)  (mi-invariant)
    int sl[4], esel[4];
#pragma unroll
    for (int t = 0; t < 4; ++t) {
        int e = 15 + c15 - (g * 4 + t);
        sl[t] = g * 16 + (e & 15);
        esel[t] = e >> 4;
    }

    v8s qwf[2][2], qrf[2][2];
#pragma unroll
    for (int mi = 0; mi < 2; ++mi)
#pragma unroll
        for (int ks = 0; ks < 2; ++ks) {
            qwf[mi][ks] = *(const v8s*)(qwp + ((i0w + mi * 16 + c15) << 6) + ks * 32 + g * 8);
            qrf[mi][ks] = *(const v8s*)(qrp + ((i0w + mi * 16 + c15) << 6) + ks * 32 + g * 8);
        }

    v4f acc_o[2][4];
    float psac[2][4];
#pragma unroll
    for (int mi = 0; mi < 2; ++mi)
#pragma unroll
        for (int df = 0; df < 4; ++df) {
            acc_o[mi][df] = v4f{0.f, 0.f, 0.f, 0.f};
            psac[mi][df] = 0.f;
        }

    uint16_t* Ptw = Ptl[w];
    const float SCL = 0.18033688f;   // 0.125 * log2(e)
    const float MB8 = 11.54156032f;  // 8 * log2(e)

    // ---- prologue staging: K/V tile 0 (chunks w, w+4) + Kr rows B0..B0+191
#pragma unroll
    for (int qq = 0; qq < 2; ++qq) {
        const int chunk = qq * 4 + w;
        gld16(ktp + (size_t)(chunk * 8 + rsub) * 128 + csrc,
              (char*)Ks[0] + chunk * 1024 + dsto);
        gld16(vtp + (size_t)(chunk * 8 + rsub) * 2048 + csrc,
              (char*)Vs[0] + chunk * 1024 + dsto);
    }
#pragma unroll
    for (int qq = 0; qq < 6; ++qq) {
        const int chunk = qq * 4 + w;
        const int rg = B0 + chunk * 8 + rsub;   // in [1, 1088]
        gld16(krp + (size_t)rg * 128 + csrc, (char*)Krs + chunk * 1024 + dsto);
    }
    asm volatile("s_waitcnt vmcnt(0)" ::: "memory");
    __syncthreads();

    for (int jt = 0; jt < 16; ++jt) {
        const int cur = jt & 1;
        if (jt < 15) {
            const int j1 = (jt + 1) * 64;
            const int sbase = (192 + 64 * jt) & 255;   // ring write slots
#pragma unroll
            for (int qq = 0; qq < 2; ++qq) {
                const int chunk = qq * 4 + w;
                gld16(ktp + (size_t)(j1 + chunk * 8 + rsub) * 128 + csrc,
                      (char*)Ks[cur ^ 1] + chunk * 1024 + dsto);
                gld16(vtp + (size_t)(chunk * 8 + rsub) * 2048 + j1 * 2 + csrc,
                      (char*)Vs[cur ^ 1] + chunk * 1024 + dsto);
                int rg = B0 + 192 + 64 * jt + chunk * 8 + rsub;
                rg = rg > 2047 ? 2047 : rg;  // clamp: only u=95 (never gathered)
                gld16(krp + (size_t)rg * 128 + csrc,
                      (char*)Krs + (sbase + chunk * 8) * 128 + dsto);
            }
        }

        // --- AC = Qw x K^T (2 mi x 64 cols), K-frags shared across mi ---
        v4f ac[2][4];
#pragma unroll
        for (int mi = 0; mi < 2; ++mi)
#pragma unroll
            for (int jf = 0; jf < 4; ++jf) ac[mi][jf] = v4f{0.f, 0.f, 0.f, 0.f};

        __builtin_amdgcn_s_setprio(1);
#pragma unroll
        for (int jf = 0; jf < 4; ++jf) {
            const char* krow = (const char*)Ks[cur] + (jf * 16 + c15) * 128;
#pragma unroll
            for (int ks = 0; ks < 2; ++ks) {
                v8s kf = *(const v8s*)(krow + ((ks * 64 + g * 16) ^ swz));
                ac[0][jf] = __builtin_amdgcn_mfma_f32_16x16x32_bf16(qwf[0][ks], kf, ac[0][jf], 0, 0, 0);
                ac[1][jf] = __builtin_amdgcn_mfma_f32_16x16x32_bf16(qwf[1][ks], kf, ac[1][jf], 0, 0, 0);
            }
        }
        // --- BD: one 96-row Kr window serves both mi (pf 0..5 shared) ---
        // pp0[k] = P(mi0, pf=k+1), pp1[k] = P(mi1, pf=k)
        v4f pp0[5], pp1[5];
#pragma unroll
        for (int pf = 0; pf < 5; ++pf) {
            pp0[pf] = v4f{0.f, 0.f, 0.f, 0.f};
            pp1[pf] = v4f{0.f, 0.f, 0.f, 0.f};
        }
        const int krbase = 64 * jt + 96 - 32 * w + c15;  // ring slot (+c15)
#pragma unroll
        for (int pf = 0; pf < 6; ++pf) {
            const int sltr = (krbase + 16 * pf) & 255;
            const char* krow = (const char*)Krs + sltr * 128;
#pragma unroll
            for (int ks = 0; ks < 2; ++ks) {
                v8s krf = *(const v8s*)(krow + ((ks * 64 + g * 16) ^ swz));
                if (pf >= 1)
                    pp0[pf - 1] = __builtin_amdgcn_mfma_f32_16x16x32_bf16(qrf[0][ks], krf, pp0[pf - 1], 0, 0, 0);
                if (pf <= 4)
                    pp1[pf] = __builtin_amdgcn_mfma_f32_16x16x32_bf16(qrf[1][ks], krf, pp1[pf], 0, 0, 0);
            }
        }
        __builtin_amdgcn_s_setprio(0);

        // --- rel-shift gather (per mi; sl is mi-invariant) ---
        float spp0[5][4], spp1[5][4];
#pragma unroll
        for (int pf = 0; pf < 5; ++pf)
#pragma unroll
            for (int t = 0; t < 4; ++t) {
                spp0[pf][t] = __shfl(pp0[pf][t], sl[t]);
                spp1[pf][t] = __shfl(pp1[pf][t], sl[t]);
            }

        // --- fixed-max softmax + packed P store, per mi-half ---
#pragma unroll
        for (int mi = 0; mi < 2; ++mi) {
#pragma unroll
            for (int t = 0; t < 4; ++t) {
                float p[4];
#pragma unroll
                for (int jf = 0; jf < 4; ++jf) {
                    float bd = mi ? (esel[t] ? spp1[jf + 1][t] : spp1[jf][t])
                                  : (esel[t] ? spp0[jf + 1][t] : spp0[jf][t]);
                    p[jf] = exp2f((ac[mi][jf][t] + bd) * SCL - MB8);
                    psac[mi][t] += p[jf];
                }
                uint32_t w0 = cvtpk(p[0], p[1]);
                uint32_t w1 = cvtpk(p[2], p[3]);
                const int rw = g * 4 + t;
                *(uint2*)((char*)Ptw + mi * 2048 + rw * 128 + ((c15 * 8) ^ ((rw & 7) << 4))) =
                    uint2{w0, w1};
            }
        }
        asm volatile("s_waitcnt lgkmcnt(0)" ::: "memory");

        // --- PV: A-frags from Ptw halves, V-frags shared across mi ---
        v8s pa[2][2];
#pragma unroll
        for (int mi = 0; mi < 2; ++mi)
#pragma unroll
            for (int ks = 0; ks < 2; ++ks)
                pa[mi][ks] = *(const v8s*)((const char*)Ptw + mi * 2048 + c15 * 128 + ((ks * 64 + g * 16) ^ swz));
        __builtin_amdgcn_s_setprio(1);
#pragma unroll
        for (int df = 0; df < 4; ++df) {
            const char* vrow = (const char*)Vs[cur] + (df * 16 + c15) * 128;
#pragma unroll
            for (int ks = 0; ks < 2; ++ks) {
                v8s vf = *(const v8s*)(vrow + ((ks * 64 + g * 16) ^ swz));
                acc_o[0][df] = __builtin_amdgcn_mfma_f32_16x16x32_bf16(pa[0][ks], vf, acc_o[0][df], 0, 0, 0);
                acc_o[1][df] = __builtin_amdgcn_mfma_f32_16x16x32_bf16(pa[1][ks], vf, acc_o[1][df], 0, 0, 0);
            }
        }
        __builtin_amdgcn_s_setprio(0);

        asm volatile("s_waitcnt vmcnt(0)" ::: "memory");
        __syncthreads();
    }

    // ---- epilogue: row-sum reduce (across c15 lanes), divide, store ----
#pragma unroll
    for (int mi = 0; mi < 2; ++mi) {
        float rinv[4];
#pragma unroll
        for (int t = 0; t < 4; ++t) {
            float l = psac[mi][t];
#pragma unroll
            for (int m = 1; m < 16; m <<= 1) l += __shfl_xor(l, m);
            rinv[t] = 1.0f / l;
        }
#pragma unroll
        for (int df = 0; df < 4; ++df)
#pragma unroll
            for (int t = 0; t < 4; ++t) {
                int i = i0w + mi * 16 + g * 4 + t;
                int d = df * 16 + c15;
                AV[((size_t)(i * 4 + b) << 10) + n * 64 + d] =
                    f2b(acc_o[mi][df][t] * rinv[t]);
            }
    }
}

// ---------------- LayerNorm over last dim (1024), one row per wave ----------
__global__ __launch_bounds__(256) void ln_kernel(
    const float* __restrict__ AO, const float* __restrict__ gamma,
    const float* __restrict__ beta, float* __restrict__ out)
{
    const int w = threadIdx.x >> 6, lane = threadIdx.x & 63;
    const int row = blockIdx.x * 4 + w;
    const float4* src = (const float4*)(AO + (size_t)row * 1024);
    float4 v[4];
    float s = 0.f, sq = 0.f;
#pragma unroll
    for (int q = 0; q < 4; ++q) {
        v[q] = src[lane + q * 64];
        s += v[q].x + v[q].y + v[q].z + v[q].w;
        sq += v[q].x * v[q].x + v[q].y * v[q].y + v[q].z * v[q].z + v[q].w * v[q].w;
    }
#pragma unroll
    for (int m = 1; m < 64; m <<= 1) { s += __shfl_xor(s, m); sq += __shfl_xor(sq, m); }
    float mean = s * (1.f / 1024.f);
    float var = sq * (1.f / 1024.f) - mean * mean;
    float rstd = rsqrtf(var + 1e-5f);
    const float4* g4 = (const float4*)gamma;
    const float4* b4 = (const float4*)beta;
    float4* o4 = (float4*)(out + (size_t)row * 1024);
#pragma unroll
    for (int q = 0; q < 4; ++q) {
        float4 gg = g4[lane + q * 64], bb = b4[lane + q * 64], vv = v[q], r;
        r.x = (vv.x - mean) * rstd * gg.x + bb.x;
        r.y = (vv.y - mean) * rstd * gg.y + bb.y;
        r.z = (vv.z - mean) * rstd * gg.z + bb.z;
        r.w = (vv.w - mean) * rstd * gg.w + bb.w;
        o4[lane + q * 64] = r;
    }
}

extern "C" void kernel_launch(void* const* d_in, const int* in_sizes, int n_in,
                              void* d_out, int out_size, void* d_ws, size_t ws_size,
                              hipStream_t stream)
{
    const float* h        = (const float*)d_in[0];
    const float* r        = (const float*)d_in[1];
    const float* q_w      = (const float*)d_in[2];
    const float* k_w      = (const float*)d_in[3];
    const float* v_w      = (const float*)d_in[4];
    const float* o_w      = (const float*)d_in[5];
    const float* r_w      = (const float*)d_in[6];
    const float* r_r_bias = (const float*)d_in[7];
    const float* r_w_bias = (const float*)d_in[8];
    const float* ln_gamma = (const float*)d_in[9];
    const float* ln_beta  = (const float*)d_in[10];
    float* out = (float*)d_out;

    char* ws = (char*)d_ws;
    const size_t MB = 1u << 20;
    uint16_t* AV   = (uint16_t*)(ws + 0);        // 8MB  [i*4+b][n*64+d] bf16
    float*    AO   = (float*)(ws + 8 * MB);      // 16MB [m][hh] f32
    uint16_t* Wcat = (uint16_t*)(ws + 24 * MB);  // 6MB  [nd' 0..3071][h] (qT,kT,vT)
    uint16_t* rwT  = (uint16_t*)(ws + 30 * MB);  // 2MB  [nd][h]
    uint16_t* owB  = (uint16_t*)(ws + 32 * MB);  // 2MB  [hh][nd]
    uint16_t* Qw   = (uint16_t*)(ws + 34 * MB);  // 8MB  [bn][i][d] (+r_w_bias)
    uint16_t* Qr   = (uint16_t*)(ws + 42 * MB);  // 8MB  [bn][i][d] (+r_r_bias)
    uint16_t* Kt   = (uint16_t*)(ws + 50 * MB);  // 8MB  [bn][i][d]
    uint16_t* Vt   = (uint16_t*)(ws + 58 * MB);  // 8MB  [bn][d][i'] (transp+perm)
    uint16_t* Kr   = (uint16_t*)(ws + 66 * MB);  // 16MB [bn][j][d]   (ends 82MB)

    prep_kernel<<<1536, 256, 0, stream>>>(o_w, q_w, k_w, v_w, r_w,
                                          (uint64_t*)owB, Wcat, rwT);
    gemm_qkvr<<<1280, 256, 0, stream>>>(h, Wcat, r, rwT,
                                        Qw, Qr, Kt, Vt, Kr, r_w_bias, r_r_bias);
    attn_kernel<<<512, 256, 0, stream>>>(Qw, Qr, Kt, Vt, Kr, AV);
    gemm_out<<<512, 256, 0, stream>>>(AV, owB, AO, h);
    ln_kernel<<<1024, 256, 0, stream>>>(AO, ln_gamma, ln_beta, out);
}